// Round 17
// baseline (156.902 us; speedup 1.0000x reference)
//
#include <hip/hip_runtime.h>
#include <cstdint>

// AttentionFlow — fused MFMA; 64-row tiles; upfront A-staging (slot0+sc
// folded), 0-barrier k-loops with 3-deep global B prefetch + 1-deep LDS af
// prefetch, c-fragment register prefetch (load-free epilogue), fused q2c
// partials, and an in-kernel per-batch flat barrier that lets each block
// compute q2c and write slot3 from registers — no tail kernel, no c re-read.
// B=8, T=2048, I=512, D=512. Output (B,T,4D) fp32.

constexpr int kB = 8;
constexpr int kT = 2048;
constexpr int kI = 512;
constexpr int kD = 512;
constexpr int kW = 4 * kD;
constexpr int kRows = 64;                // t-rows per block
constexpr int kTiles = kT / kRows;       // 32 tiles per batch
constexpr int kChunk = kRows * 72;       // LDS bytes per k-chunk (4608)

using f32x4  = __attribute__((ext_vector_type(4))) float;
using bf16x4 = __attribute__((ext_vector_type(4))) __bf16;
using bf16x8 = __attribute__((ext_vector_type(8))) __bf16;

__device__ __forceinline__ float dot8(const f32x4& a0, const f32x4& a1,
                                      const f32x4& b0, const f32x4& b1) {
  return a0.x * b0.x + a0.y * b0.y + a0.z * b0.z + a0.w * b0.w +
         a1.x * b1.x + a1.y * b1.y + a1.z * b1.z + a1.w * b1.w;
}

// Combined prep: blocks [0,32) do qf+sq; blocks [32,96) do vf transpose.
// Block (0,b) also zeroes ctr[b] (must be reset every call: harness does not
// re-poison ws between replays).
__global__ __launch_bounds__(256) void prep_kernel(
    const float* __restrict__ q, const float* __restrict__ w_q,
    const float* __restrict__ b_q, float* __restrict__ sq,
    __bf16* __restrict__ qf, __bf16* __restrict__ vf, int* __restrict__ ctr) {
  const int b = blockIdx.y;
  const int tid = threadIdx.x;
  if (blockIdx.x == 0 && tid == 0) ctr[b] = 0;
  if (blockIdx.x < 32) {
    __shared__ float sacc[16][17];
    const int g = blockIdx.x;
    const int kk0 = tid >> 6;
    const int lane = tid & 63;
    const int lr = lane & 15, lg = lane >> 4;
    const float* row = q + ((size_t)(b * kI + g * 16 + lr)) * kD;
    float sp = 0.f;
#pragma unroll
    for (int kk = kk0; kk < 16; kk += 4) {
      const int ka = kk * 32 + lg * 8;
      f32x4 v0 = *(const f32x4*)(row + ka);
      f32x4 v1 = *(const f32x4*)(row + ka + 4);
      f32x4 u0 = *(const f32x4*)(w_q + ka);
      f32x4 u1 = *(const f32x4*)(w_q + ka + 4);
      sp += dot8(v0, v1, u0, u1);
      bf16x8 o = {(__bf16)v0.x, (__bf16)v0.y, (__bf16)v0.z, (__bf16)v0.w,
                  (__bf16)v1.x, (__bf16)v1.y, (__bf16)v1.z, (__bf16)v1.w};
      *(bf16x8*)(qf + ((((size_t)(b * 32 + g)) * 16 + kk) << 9) + lane * 8) = o;
    }
    sacc[lr][kk0 * 4 + lg] = sp;
    __syncthreads();
    if (tid < 16) {
      float s = 0.f;
#pragma unroll
      for (int j = 0; j < 16; ++j) s += sacc[tid][j];
      sq[b * kI + g * 16 + tid] = s + b_q[0];
    }
  } else {
    __shared__ float ts[64][68];
    const int blk = blockIdx.x - 32;   // 0..63
    const int i0 = (blk & 7) * 64;
    const int d0 = (blk >> 3) * 64;
    const int r = tid >> 2;
    const int cg = (tid & 3) * 16;
#pragma unroll
    for (int j = 0; j < 4; ++j) {
      f32x4 v = *(const f32x4*)(q + ((size_t)(b * kI + i0 + r)) * kD + d0 + cg + 4 * j);
      ts[r][cg + 4 * j + 0] = v.x;
      ts[r][cg + 4 * j + 1] = v.y;
      ts[r][cg + 4 * j + 2] = v.z;
      ts[r][cg + 4 * j + 3] = v.w;
    }
    __syncthreads();
    const int dl = tid >> 2;
    const int ig = (tid & 3) * 16;
    bf16x8 o0, o1;
#pragma unroll
    for (int j = 0; j < 8; ++j) o0[j] = (__bf16)ts[ig + j][dl];
#pragma unroll
    for (int j = 0; j < 8; ++j) o1[j] = (__bf16)ts[ig + 8 + j][dl];
    const int gd = (d0 >> 4) + (dl >> 4);
    const int lr = dl & 15;
    const int kki0 = (i0 >> 5) + (ig >> 5);
    const int lg0 = (ig & 31) >> 3;
    const int i1 = ig + 8;
    const int kki1 = (i0 >> 5) + (i1 >> 5);
    const int lg1 = (i1 & 31) >> 3;
    *(bf16x8*)(vf + ((((size_t)(b * 32 + gd)) * 16 + kki0) << 9) +
               (lg0 * 16 + lr) * 8) = o0;
    *(bf16x8*)(vf + ((((size_t)(b * 32 + gd)) * 16 + kki1) << 9) +
               (lg1 * 16 + lr) * 8) = o1;
  }
}

__global__ __launch_bounds__(512, 1) void fused_attn(
    const float* __restrict__ c, const __bf16* __restrict__ qf,
    const __bf16* __restrict__ vf, const float* __restrict__ w_cq,
    const float* __restrict__ w_c, const float* __restrict__ b_c,
    const float* __restrict__ b_cq, const float* __restrict__ sq,
    float* __restrict__ out, float* __restrict__ mz,
    float* __restrict__ u_tile, int* __restrict__ ctr) {
  // lAP: 16 k-chunks x 64 rows x 72B (A in phase 1, P in phase 2) = 73728 B
  __shared__ __align__(16) char lAP[16 * kChunk];
  __shared__ float scrow[kRows];
  __shared__ float redm[8 * kRows];
  __shared__ float reds[8 * kRows];
  __shared__ float sq2c[kD];

  const int b = blockIdx.y;
  const int tile = blockIdx.x;
  const int t0 = tile * kRows;
  const int tid = threadIdx.x;
  const int w = tid >> 6;  // 0..7: 64-wide i (phase1) / d (phase2) slice
  const int lane = tid & 63;
  const int lr = lane & 15, lg = lane >> 4;

  // ---- phase-1 B prefetch issued first (flies under c staging) ----------
  const __bf16* qfb = qf + (((size_t)(b * 32 + w * 4)) * 16 << 9) + lane * 8;
  bf16x8 b0[4], b1[4], b2[4], b3[4];
#pragma unroll
  for (int n4 = 0; n4 < 4; ++n4)
    b0[n4] = *(const bf16x8*)(qfb + (((size_t)(n4 * 16 + 0)) << 9));
#pragma unroll
  for (int n4 = 0; n4 < 4; ++n4)
    b1[n4] = *(const bf16x8*)(qfb + (((size_t)(n4 * 16 + 1)) << 9));
#pragma unroll
  for (int n4 = 0; n4 < 4; ++n4)
    b2[n4] = *(const bf16x8*)(qfb + (((size_t)(n4 * 16 + 2)) << 9));

  // ---- stage A = bf16(c .* w_cq) -> lAP; slot0=c; sc rowdot folded ------
  {
    const int srow = tid >> 3;       // 0..63
    const int col4 = (tid & 7) * 4;  // 0..28
    const float* crow = c + ((size_t)(b * kT + t0 + srow)) * kD;
    float* orow0 = out + ((size_t)(b * kT + t0 + srow)) * kW;
    float scp = 0.f;
#pragma unroll
    for (int j = 0; j < 16; ++j) {
      const int col = col4 + j * 32;
      f32x4 v = *(const f32x4*)(crow + col);
      *(f32x4*)(orow0 + col) = v;  // slot0 = c (early, spreads write burst)
      const f32x4 wq = *(const f32x4*)(w_cq + col);
      const f32x4 wc = *(const f32x4*)(w_c + col);
      scp += v.x * wc.x + v.y * wc.y + v.z * wc.z + v.w * wc.w;
      v *= wq;
      bf16x4 bv = {(__bf16)v.x, (__bf16)v.y, (__bf16)v.z, (__bf16)v.w};
      *(bf16x4*)(lAP + j * kChunk + srow * 72 + col4 * 2) = bv;
    }
    scp += __shfl_xor(scp, 1, 64);
    scp += __shfl_xor(scp, 2, 64);
    scp += __shfl_xor(scp, 4, 64);
    if ((tid & 7) == 0) scrow[srow] = scp + b_c[0];
  }
  __syncthreads();

  // ---- Phase 1: S = A @ qf (0 barriers, 3-deep B + 1-deep af prefetch) --
  f32x4 acc[4][4] = {};
  bf16x8 afc[4], afn[4];
#pragma unroll
  for (int m = 0; m < 4; ++m)
    afc[m] = *(const bf16x8*)(lAP + 0 * kChunk + (m * 16 + lr) * 72 + lg * 16);
#pragma unroll
  for (int kk = 0; kk < 16; ++kk) {
    if (kk < 13) {
#pragma unroll
      for (int n4 = 0; n4 < 4; ++n4)
        b3[n4] = *(const bf16x8*)(qfb + (((size_t)(n4 * 16 + kk + 3)) << 9));
    }
    if (kk < 15) {
#pragma unroll
      for (int m = 0; m < 4; ++m)
        afn[m] = *(const bf16x8*)(lAP + (kk + 1) * kChunk + (m * 16 + lr) * 72 +
                                  lg * 16);
    }
#pragma unroll
    for (int m = 0; m < 4; ++m)
#pragma unroll
      for (int n4 = 0; n4 < 4; ++n4)
        acc[m][n4] = __builtin_amdgcn_mfma_f32_16x16x32_bf16(afc[m], b0[n4],
                                                             acc[m][n4], 0, 0, 0);
#pragma unroll
    for (int m = 0; m < 4; ++m) afc[m] = afn[m];
#pragma unroll
    for (int n4 = 0; n4 < 4; ++n4) {
      b0[n4] = b1[n4];
      b1[n4] = b2[n4];
      b2[n4] = b3[n4];
    }
  }

  // biases
  const float bq = b_cq[0];
  float sqv[4];
#pragma unroll
  for (int n4 = 0; n4 < 4; ++n4) sqv[n4] = sq[b * kI + w * 64 + n4 * 16 + lr];
  float scr[4][4];
#pragma unroll
  for (int m = 0; m < 4; ++m)
#pragma unroll
    for (int r = 0; r < 4; ++r) scr[m][r] = scrow[m * 16 + lg * 4 + r] + bq;
#pragma unroll
  for (int m = 0; m < 4; ++m)
#pragma unroll
    for (int n4 = 0; n4 < 4; ++n4)
#pragma unroll
      for (int r = 0; r < 4; ++r) acc[m][n4][r] += scr[m][r] + sqv[n4];

  // ---------------- exact softmax over i (512) ---------------------------
  float mx[4][4];
#pragma unroll
  for (int m = 0; m < 4; ++m)
#pragma unroll
    for (int r = 0; r < 4; ++r) {
      float v = acc[m][0][r];
#pragma unroll
      for (int n4 = 1; n4 < 4; ++n4) v = fmaxf(v, acc[m][n4][r]);
#pragma unroll
      for (int off = 1; off <= 8; off <<= 1) v = fmaxf(v, __shfl_xor(v, off, 64));
      mx[m][r] = v;
    }
  if (lr == 0) {
#pragma unroll
    for (int m = 0; m < 4; ++m)
#pragma unroll
      for (int r = 0; r < 4; ++r)
        redm[w * kRows + m * 16 + lg * 4 + r] = mx[m][r];
  }
  __syncthreads();
#pragma unroll
  for (int m = 0; m < 4; ++m)
#pragma unroll
    for (int r = 0; r < 4; ++r) {
      const int rw = m * 16 + lg * 4 + r;
      float v = redm[rw];
#pragma unroll
      for (int w2 = 1; w2 < 8; ++w2) v = fmaxf(v, redm[w2 * kRows + rw]);
      mx[m][r] = v;
    }

  float sm[4][4] = {};
#pragma unroll
  for (int m = 0; m < 4; ++m)
#pragma unroll
    for (int n4 = 0; n4 < 4; ++n4)
#pragma unroll
      for (int r = 0; r < 4; ++r) {
        const float p = __expf(acc[m][n4][r] - mx[m][r]);
        acc[m][n4][r] = p;
        sm[m][r] += p;
      }
#pragma unroll
  for (int m = 0; m < 4; ++m)
#pragma unroll
    for (int r = 0; r < 4; ++r)
#pragma unroll
      for (int off = 1; off <= 8; off <<= 1)
        sm[m][r] += __shfl_xor(sm[m][r], off, 64);
  if (lr == 0) {
#pragma unroll
    for (int m = 0; m < 4; ++m)
#pragma unroll
      for (int r = 0; r < 4; ++r)
        reds[w * kRows + m * 16 + lg * 4 + r] = sm[m][r];
  }
  __syncthreads();
  float inv[4][4];
#pragma unroll
  for (int m = 0; m < 4; ++m)
#pragma unroll
    for (int r = 0; r < 4; ++r) {
      const int rw = m * 16 + lg * 4 + r;
      float v = reds[rw];
#pragma unroll
      for (int w2 = 1; w2 < 8; ++w2) v += reds[w2 * kRows + rw];
      inv[m][r] = 1.f / v;
    }

  // -------- prefetch phase-2 first B frags (overlap with P publish) ------
  const __bf16* vfb = vf + (((size_t)(b * 32 + w * 4)) * 16 << 9) + lane * 8;
  bf16x8 v0_[4], v1_[4], v2_[4], v3_[4];
#pragma unroll
  for (int n4 = 0; n4 < 4; ++n4)
    v0_[n4] = *(const bf16x8*)(vfb + (((size_t)(n4 * 16 + 0)) << 9));
#pragma unroll
  for (int n4 = 0; n4 < 4; ++n4)
    v1_[n4] = *(const bf16x8*)(vfb + (((size_t)(n4 * 16 + 1)) << 9));
#pragma unroll
  for (int n4 = 0; n4 < 4; ++n4)
    v2_[n4] = *(const bf16x8*)(vfb + (((size_t)(n4 * 16 + 2)) << 9));

  // ---------------- P (bf16) -> lAP (aliases A), k-chunked ---------------
#pragma unroll
  for (int m = 0; m < 4; ++m)
#pragma unroll
    for (int r = 0; r < 4; ++r) {
      const int trow = m * 16 + lg * 4 + r;
#pragma unroll
      for (int n4 = 0; n4 < 4; ++n4) {
        const int icol = w * 64 + n4 * 16 + lr;
        const int kkc = icol >> 5, kc = icol & 31;
        *(__bf16*)(lAP + kkc * kChunk + trow * 72 + kc * 2) =
            (__bf16)(acc[m][n4][r] * inv[m][r]);
      }
    }
  __syncthreads();

  // ---- c-fragment prefetch for the epilogue (hidden under phase 2) ------
  float cfrag[4][4][4];
#pragma unroll
  for (int m = 0; m < 4; ++m)
#pragma unroll
    for (int r = 0; r < 4; ++r) {
      const float* crow2 =
          c + ((size_t)(b * kT + t0 + m * 16 + lg * 4 + r)) * kD + w * 64 + lr;
#pragma unroll
      for (int n4 = 0; n4 < 4; ++n4) cfrag[m][n4][r] = crow2[n4 * 16];
    }

  // ---- Phase 2: O = P @ vf (0 barriers, 3-deep B + 1-deep af prefetch) --
  f32x4 o[4][4] = {};
  bf16x8 pfc[4], pfn[4];
#pragma unroll
  for (int m = 0; m < 4; ++m)
    pfc[m] = *(const bf16x8*)(lAP + 0 * kChunk + (m * 16 + lr) * 72 + lg * 16);
#pragma unroll
  for (int kki = 0; kki < 16; ++kki) {
    if (kki < 13) {
#pragma unroll
      for (int n4 = 0; n4 < 4; ++n4)
        v3_[n4] = *(const bf16x8*)(vfb + (((size_t)(n4 * 16 + kki + 3)) << 9));
    }
    if (kki < 15) {
#pragma unroll
      for (int m = 0; m < 4; ++m)
        pfn[m] = *(const bf16x8*)(lAP + (kki + 1) * kChunk + (m * 16 + lr) * 72 +
                                  lg * 16);
    }
#pragma unroll
    for (int m = 0; m < 4; ++m)
#pragma unroll
      for (int n4 = 0; n4 < 4; ++n4)
        o[m][n4] = __builtin_amdgcn_mfma_f32_16x16x32_bf16(pfc[m], v0_[n4],
                                                           o[m][n4], 0, 0, 0);
#pragma unroll
    for (int m = 0; m < 4; ++m) pfc[m] = pfn[m];
#pragma unroll
    for (int n4 = 0; n4 < 4; ++n4) {
      v0_[n4] = v1_[n4];
      v1_[n4] = v2_[n4];
      v2_[n4] = v3_[n4];
    }
  }

  // ---- epilogue: slots [c2q | c*c2q] — pure stores (c in registers) -----
  float m_tile;
  {
    float v = mx[0][0];
#pragma unroll
    for (int m = 0; m < 4; ++m)
#pragma unroll
      for (int r = 0; r < 4; ++r) v = fmaxf(v, mx[m][r]);
    v = fmaxf(v, __shfl_xor(v, 16, 64));
    v = fmaxf(v, __shfl_xor(v, 32, 64));
    m_tile = v;
  }
  float u[4] = {};
  float zz = 0.f;
#pragma unroll
  for (int m = 0; m < 4; ++m)
#pragma unroll
    for (int r = 0; r < 4; ++r) {
      const int t = t0 + m * 16 + lg * 4 + r;
      const size_t rb = (size_t)(b * kT + t);
      float* orow = out + rb * kW;
      const float ev = __expf(mx[m][r] - m_tile);
      zz += ev;
#pragma unroll
      for (int n4 = 0; n4 < 4; ++n4) {
        const int d = w * 64 + n4 * 16 + lr;
        const float cvv = cfrag[m][n4][r];
        const float pv = o[m][n4][r];
        orow[kD + d] = pv;
        orow[2 * kD + d] = cvv * pv;
        u[n4] += ev * cvv;
      }
    }
#pragma unroll
  for (int n4 = 0; n4 < 4; ++n4) {
    u[n4] += __shfl_xor(u[n4], 16, 64);
    u[n4] += __shfl_xor(u[n4], 32, 64);
  }
  if (lg == 0) {
    float* ub = u_tile + ((size_t)(b * kTiles + tile)) * kD;
#pragma unroll
    for (int n4 = 0; n4 < 4; ++n4) ub[w * 64 + n4 * 16 + lr] = u[n4];
  }
  if (w == 0) {
    zz += __shfl_xor(zz, 16, 64);
    zz += __shfl_xor(zz, 32, 64);
    if (lane == 0) {
      mz[b * 64 + tile] = m_tile;
      mz[b * 64 + 32 + tile] = zz;
    }
  }

  // ====== per-batch flat barrier: wait for all 32 tiles of batch b =======
  __threadfence();   // each thread makes its mz/u_tile stores agent-visible
  __syncthreads();   // whole block done + fenced
  if (tid == 0) {
    __hip_atomic_fetch_add(&ctr[b], 1, __ATOMIC_ACQ_REL,
                           __HIP_MEMORY_SCOPE_AGENT);
    while (__hip_atomic_load(&ctr[b], __ATOMIC_ACQUIRE,
                             __HIP_MEMORY_SCOPE_AGENT) < kTiles) {
    }
  }
  __syncthreads();

  // ====== q2c[b,:] from mz + u_tile (all tiles now visible) ==============
  if (tid < 64) redm[tid] = mz[b * 64 + tid];
  __syncthreads();
  {
    float M = redm[0];
#pragma unroll
    for (int k = 1; k < 32; ++k) M = fmaxf(M, redm[k]);
    float Z = 0.f;
    float s = 0.f;
#pragma unroll
    for (int k = 0; k < 32; ++k) {
      const float wk = __expf(redm[k] - M);
      Z += wk * redm[32 + k];
      s += wk * u_tile[((size_t)(b * kTiles + k)) * kD + tid];
    }
    sq2c[tid] = s / Z;
  }
  __syncthreads();

  // ====== slot3 = cfrag * q2c — zero loads beyond LDS ====================
#pragma unroll
  for (int m = 0; m < 4; ++m)
#pragma unroll
    for (int r = 0; r < 4; ++r) {
      const int t = t0 + m * 16 + lg * 4 + r;
      float* orow3 = out + ((size_t)(b * kT + t)) * kW + 3 * kD;
#pragma unroll
      for (int n4 = 0; n4 < 4; ++n4) {
        const int d = w * 64 + n4 * 16 + lr;
        orow3[d] = cfrag[m][n4][r] * sq2c[d];
      }
    }
}

extern "C" void kernel_launch(void* const* d_in, const int* in_sizes, int n_in,
                              void* d_out, int out_size, void* d_ws, size_t ws_size,
                              hipStream_t stream) {
  const float* c    = (const float*)d_in[0];
  const float* q    = (const float*)d_in[1];
  const float* w_c  = (const float*)d_in[2];
  const float* b_c  = (const float*)d_in[3];
  const float* w_q  = (const float*)d_in[4];
  const float* b_q  = (const float*)d_in[5];
  const float* w_cq = (const float*)d_in[6];
  const float* b_cq = (const float*)d_in[7];
  float* out = (float*)d_out;
  float* ws = (float*)d_ws;

  // ws layout (floats): sq 4096 | mz 512 | u_tile 131072 | ctr 8 ints ;
  // then bf16: qf 2M | vf 2M   (~9 MB total)
  float* sq     = ws;
  float* mz     = sq + kB * kI;
  float* u_tile = mz + kB * 64;
  int*   ctr    = (int*)(u_tile + (size_t)kB * kTiles * kD);
  __bf16* qf = (__bf16*)(ctr + 8);
  __bf16* vf = qf + (size_t)kB * kI * kD;

  dim3 gp(96, kB);  // 32 qf-blocks + 64 vf-blocks per batch; (0,b) zeroes ctr
  prep_kernel<<<gp, 256, 0, stream>>>(q, w_q, b_q, sq, qf, vf, ctr);

  dim3 gf(kTiles, kB);  // 32 x 8 = 256 blocks = 1/CU (all co-resident)
  fused_attn<<<gf, 512, 0, stream>>>(c, qf, vf, w_cq, w_c, b_c, b_cq, sq, out,
                                     mz, u_tile, ctr);
}

// Round 18
// 68.040 us; speedup vs baseline: 2.3060x; 2.3060x over previous
//
#include <hip/hip_runtime.h>
#include <cstdint>

// AttentionFlow — fused MFMA; 64-row tiles; batched-load A-staging (slot0+sc
// folded), 0-barrier k-loops with 3-deep global B prefetch + 1-deep LDS af
// prefetch, c-fragment register prefetch (load-free epilogue), fused q2c
// partials, merged prep kernel, slot3+merge tail reading slot0 from out (L3).
// B=8, T=2048, I=512, D=512. Output (B,T,4D) fp32.

constexpr int kB = 8;
constexpr int kT = 2048;
constexpr int kI = 512;
constexpr int kD = 512;
constexpr int kW = 4 * kD;
constexpr int kRows = 64;                // t-rows per block
constexpr int kTiles = kT / kRows;       // 32 tiles per batch
constexpr int kChunk = kRows * 72;       // LDS bytes per k-chunk (4608)

using f32x4  = __attribute__((ext_vector_type(4))) float;
using bf16x4 = __attribute__((ext_vector_type(4))) __bf16;
using bf16x8 = __attribute__((ext_vector_type(8))) __bf16;

__device__ __forceinline__ float dot8(const f32x4& a0, const f32x4& a1,
                                      const f32x4& b0, const f32x4& b1) {
  return a0.x * b0.x + a0.y * b0.y + a0.z * b0.z + a0.w * b0.w +
         a1.x * b1.x + a1.y * b1.y + a1.z * b1.z + a1.w * b1.w;
}

// Combined prep: blocks [0,32) do qf+sq; blocks [32,96) do vf transpose.
__global__ __launch_bounds__(256) void prep_kernel(
    const float* __restrict__ q, const float* __restrict__ w_q,
    const float* __restrict__ b_q, float* __restrict__ sq,
    __bf16* __restrict__ qf, __bf16* __restrict__ vf) {
  const int b = blockIdx.y;
  const int tid = threadIdx.x;
  if (blockIdx.x < 32) {
    __shared__ float sacc[16][17];
    const int g = blockIdx.x;
    const int kk0 = tid >> 6;
    const int lane = tid & 63;
    const int lr = lane & 15, lg = lane >> 4;
    const float* row = q + ((size_t)(b * kI + g * 16 + lr)) * kD;
    float sp = 0.f;
#pragma unroll
    for (int kk = kk0; kk < 16; kk += 4) {
      const int ka = kk * 32 + lg * 8;
      f32x4 v0 = *(const f32x4*)(row + ka);
      f32x4 v1 = *(const f32x4*)(row + ka + 4);
      f32x4 u0 = *(const f32x4*)(w_q + ka);
      f32x4 u1 = *(const f32x4*)(w_q + ka + 4);
      sp += dot8(v0, v1, u0, u1);
      bf16x8 o = {(__bf16)v0.x, (__bf16)v0.y, (__bf16)v0.z, (__bf16)v0.w,
                  (__bf16)v1.x, (__bf16)v1.y, (__bf16)v1.z, (__bf16)v1.w};
      *(bf16x8*)(qf + ((((size_t)(b * 32 + g)) * 16 + kk) << 9) + lane * 8) = o;
    }
    sacc[lr][kk0 * 4 + lg] = sp;
    __syncthreads();
    if (tid < 16) {
      float s = 0.f;
#pragma unroll
      for (int j = 0; j < 16; ++j) s += sacc[tid][j];
      sq[b * kI + g * 16 + tid] = s + b_q[0];
    }
  } else {
    __shared__ float ts[64][68];
    const int blk = blockIdx.x - 32;   // 0..63
    const int i0 = (blk & 7) * 64;
    const int d0 = (blk >> 3) * 64;
    const int r = tid >> 2;
    const int cg = (tid & 3) * 16;
#pragma unroll
    for (int j = 0; j < 4; ++j) {
      f32x4 v = *(const f32x4*)(q + ((size_t)(b * kI + i0 + r)) * kD + d0 + cg + 4 * j);
      ts[r][cg + 4 * j + 0] = v.x;
      ts[r][cg + 4 * j + 1] = v.y;
      ts[r][cg + 4 * j + 2] = v.z;
      ts[r][cg + 4 * j + 3] = v.w;
    }
    __syncthreads();
    const int dl = tid >> 2;
    const int ig = (tid & 3) * 16;
    bf16x8 o0, o1;
#pragma unroll
    for (int j = 0; j < 8; ++j) o0[j] = (__bf16)ts[ig + j][dl];
#pragma unroll
    for (int j = 0; j < 8; ++j) o1[j] = (__bf16)ts[ig + 8 + j][dl];
    const int gd = (d0 >> 4) + (dl >> 4);
    const int lr = dl & 15;
    const int kki0 = (i0 >> 5) + (ig >> 5);
    const int lg0 = (ig & 31) >> 3;
    const int i1 = ig + 8;
    const int kki1 = (i0 >> 5) + (i1 >> 5);
    const int lg1 = (i1 & 31) >> 3;
    *(bf16x8*)(vf + ((((size_t)(b * 32 + gd)) * 16 + kki0) << 9) +
               (lg0 * 16 + lr) * 8) = o0;
    *(bf16x8*)(vf + ((((size_t)(b * 32 + gd)) * 16 + kki1) << 9) +
               (lg1 * 16 + lr) * 8) = o1;
  }
}

__global__ __launch_bounds__(512, 1) void fused_attn(
    const float* __restrict__ c, const __bf16* __restrict__ qf,
    const __bf16* __restrict__ vf, const float* __restrict__ w_cq,
    const float* __restrict__ w_c, const float* __restrict__ b_c,
    const float* __restrict__ b_cq, const float* __restrict__ sq,
    float* __restrict__ out, float* __restrict__ mz,
    float* __restrict__ u_tile) {
  // lAP: 16 k-chunks x 64 rows x 72B (A in phase 1, P in phase 2) = 73728 B
  __shared__ __align__(16) char lAP[16 * kChunk];
  __shared__ float scrow[kRows];
  __shared__ float redm[8 * kRows];
  __shared__ float reds[8 * kRows];

  const int b = blockIdx.y;
  const int tile = blockIdx.x;
  const int t0 = tile * kRows;
  const int tid = threadIdx.x;
  const int w = tid >> 6;  // 0..7: 64-wide i (phase1) / d (phase2) slice
  const int lane = tid & 63;
  const int lr = lane & 15, lg = lane >> 4;

  // ---- phase-1 B prefetch issued first (flies under c staging) ----------
  const __bf16* qfb = qf + (((size_t)(b * 32 + w * 4)) * 16 << 9) + lane * 8;
  bf16x8 b0[4], b1[4], b2[4], b3[4];
#pragma unroll
  for (int n4 = 0; n4 < 4; ++n4)
    b0[n4] = *(const bf16x8*)(qfb + (((size_t)(n4 * 16 + 0)) << 9));
#pragma unroll
  for (int n4 = 0; n4 < 4; ++n4)
    b1[n4] = *(const bf16x8*)(qfb + (((size_t)(n4 * 16 + 1)) << 9));
#pragma unroll
  for (int n4 = 0; n4 < 4; ++n4)
    b2[n4] = *(const bf16x8*)(qfb + (((size_t)(n4 * 16 + 2)) << 9));

  // ---- stage A = bf16(c .* w_cq) -> lAP; batched c loads (16 in flight);
  //      slot0=c; sc rowdot folded ----------------------------------------
  {
    const int srow = tid >> 3;       // 0..63
    const int col4 = (tid & 7) * 4;  // 0..28
    const float* crow = c + ((size_t)(b * kT + t0 + srow)) * kD;
    float* orow0 = out + ((size_t)(b * kT + t0 + srow)) * kW;
    f32x4 vbuf[16];
#pragma unroll
    for (int j = 0; j < 16; ++j)
      vbuf[j] = *(const f32x4*)(crow + col4 + j * 32);
    float scp = 0.f;
#pragma unroll
    for (int j = 0; j < 16; ++j) {
      const int col = col4 + j * 32;
      f32x4 v = vbuf[j];
      *(f32x4*)(orow0 + col) = v;  // slot0 = c (early, spreads write burst)
      const f32x4 wq = *(const f32x4*)(w_cq + col);
      const f32x4 wc = *(const f32x4*)(w_c + col);
      scp += v.x * wc.x + v.y * wc.y + v.z * wc.z + v.w * wc.w;
      v *= wq;
      bf16x4 bv = {(__bf16)v.x, (__bf16)v.y, (__bf16)v.z, (__bf16)v.w};
      *(bf16x4*)(lAP + j * kChunk + srow * 72 + col4 * 2) = bv;
    }
    scp += __shfl_xor(scp, 1, 64);
    scp += __shfl_xor(scp, 2, 64);
    scp += __shfl_xor(scp, 4, 64);
    if ((tid & 7) == 0) scrow[srow] = scp + b_c[0];
  }
  __syncthreads();

  // ---- Phase 1: S = A @ qf (0 barriers, 3-deep B + 1-deep af prefetch) --
  f32x4 acc[4][4] = {};
  bf16x8 afc[4], afn[4];
#pragma unroll
  for (int m = 0; m < 4; ++m)
    afc[m] = *(const bf16x8*)(lAP + 0 * kChunk + (m * 16 + lr) * 72 + lg * 16);
#pragma unroll
  for (int kk = 0; kk < 16; ++kk) {
    if (kk < 13) {
#pragma unroll
      for (int n4 = 0; n4 < 4; ++n4)
        b3[n4] = *(const bf16x8*)(qfb + (((size_t)(n4 * 16 + kk + 3)) << 9));
    }
    if (kk < 15) {
#pragma unroll
      for (int m = 0; m < 4; ++m)
        afn[m] = *(const bf16x8*)(lAP + (kk + 1) * kChunk + (m * 16 + lr) * 72 +
                                  lg * 16);
    }
#pragma unroll
    for (int m = 0; m < 4; ++m)
#pragma unroll
      for (int n4 = 0; n4 < 4; ++n4)
        acc[m][n4] = __builtin_amdgcn_mfma_f32_16x16x32_bf16(afc[m], b0[n4],
                                                             acc[m][n4], 0, 0, 0);
#pragma unroll
    for (int m = 0; m < 4; ++m) afc[m] = afn[m];
#pragma unroll
    for (int n4 = 0; n4 < 4; ++n4) {
      b0[n4] = b1[n4];
      b1[n4] = b2[n4];
      b2[n4] = b3[n4];
    }
  }

  // biases
  const float bq = b_cq[0];
  float sqv[4];
#pragma unroll
  for (int n4 = 0; n4 < 4; ++n4) sqv[n4] = sq[b * kI + w * 64 + n4 * 16 + lr];
  float scr[4][4];
#pragma unroll
  for (int m = 0; m < 4; ++m)
#pragma unroll
    for (int r = 0; r < 4; ++r) scr[m][r] = scrow[m * 16 + lg * 4 + r] + bq;
#pragma unroll
  for (int m = 0; m < 4; ++m)
#pragma unroll
    for (int n4 = 0; n4 < 4; ++n4)
#pragma unroll
      for (int r = 0; r < 4; ++r) acc[m][n4][r] += scr[m][r] + sqv[n4];

  // ---------------- exact softmax over i (512) ---------------------------
  float mx[4][4];
#pragma unroll
  for (int m = 0; m < 4; ++m)
#pragma unroll
    for (int r = 0; r < 4; ++r) {
      float v = acc[m][0][r];
#pragma unroll
      for (int n4 = 1; n4 < 4; ++n4) v = fmaxf(v, acc[m][n4][r]);
#pragma unroll
      for (int off = 1; off <= 8; off <<= 1) v = fmaxf(v, __shfl_xor(v, off, 64));
      mx[m][r] = v;
    }
  if (lr == 0) {
#pragma unroll
    for (int m = 0; m < 4; ++m)
#pragma unroll
      for (int r = 0; r < 4; ++r)
        redm[w * kRows + m * 16 + lg * 4 + r] = mx[m][r];
  }
  __syncthreads();
#pragma unroll
  for (int m = 0; m < 4; ++m)
#pragma unroll
    for (int r = 0; r < 4; ++r) {
      const int rw = m * 16 + lg * 4 + r;
      float v = redm[rw];
#pragma unroll
      for (int w2 = 1; w2 < 8; ++w2) v = fmaxf(v, redm[w2 * kRows + rw]);
      mx[m][r] = v;
    }

  float sm[4][4] = {};
#pragma unroll
  for (int m = 0; m < 4; ++m)
#pragma unroll
    for (int n4 = 0; n4 < 4; ++n4)
#pragma unroll
      for (int r = 0; r < 4; ++r) {
        const float p = __expf(acc[m][n4][r] - mx[m][r]);
        acc[m][n4][r] = p;
        sm[m][r] += p;
      }
#pragma unroll
  for (int m = 0; m < 4; ++m)
#pragma unroll
    for (int r = 0; r < 4; ++r)
#pragma unroll
      for (int off = 1; off <= 8; off <<= 1)
        sm[m][r] += __shfl_xor(sm[m][r], off, 64);
  if (lr == 0) {
#pragma unroll
    for (int m = 0; m < 4; ++m)
#pragma unroll
      for (int r = 0; r < 4; ++r)
        reds[w * kRows + m * 16 + lg * 4 + r] = sm[m][r];
  }
  __syncthreads();
  float inv[4][4];
#pragma unroll
  for (int m = 0; m < 4; ++m)
#pragma unroll
    for (int r = 0; r < 4; ++r) {
      const int rw = m * 16 + lg * 4 + r;
      float v = reds[rw];
#pragma unroll
      for (int w2 = 1; w2 < 8; ++w2) v += reds[w2 * kRows + rw];
      inv[m][r] = 1.f / v;
    }

  // -------- prefetch phase-2 first B frags (overlap with P publish) ------
  const __bf16* vfb = vf + (((size_t)(b * 32 + w * 4)) * 16 << 9) + lane * 8;
  bf16x8 v0_[4], v1_[4], v2_[4], v3_[4];
#pragma unroll
  for (int n4 = 0; n4 < 4; ++n4)
    v0_[n4] = *(const bf16x8*)(vfb + (((size_t)(n4 * 16 + 0)) << 9));
#pragma unroll
  for (int n4 = 0; n4 < 4; ++n4)
    v1_[n4] = *(const bf16x8*)(vfb + (((size_t)(n4 * 16 + 1)) << 9));
#pragma unroll
  for (int n4 = 0; n4 < 4; ++n4)
    v2_[n4] = *(const bf16x8*)(vfb + (((size_t)(n4 * 16 + 2)) << 9));

  // ---------------- P (bf16) -> lAP (aliases A), k-chunked ---------------
#pragma unroll
  for (int m = 0; m < 4; ++m)
#pragma unroll
    for (int r = 0; r < 4; ++r) {
      const int trow = m * 16 + lg * 4 + r;
#pragma unroll
      for (int n4 = 0; n4 < 4; ++n4) {
        const int icol = w * 64 + n4 * 16 + lr;
        const int kkc = icol >> 5, kc = icol & 31;
        *(__bf16*)(lAP + kkc * kChunk + trow * 72 + kc * 2) =
            (__bf16)(acc[m][n4][r] * inv[m][r]);
      }
    }
  __syncthreads();

  // ---- c-fragment prefetch for the epilogue (hidden under phase 2) ------
  float cfrag[4][4][4];
#pragma unroll
  for (int m = 0; m < 4; ++m)
#pragma unroll
    for (int r = 0; r < 4; ++r) {
      const float* crow2 =
          c + ((size_t)(b * kT + t0 + m * 16 + lg * 4 + r)) * kD + w * 64 + lr;
#pragma unroll
      for (int n4 = 0; n4 < 4; ++n4) cfrag[m][n4][r] = crow2[n4 * 16];
    }

  // ---- Phase 2: O = P @ vf (0 barriers, 3-deep B + 1-deep af prefetch) --
  f32x4 o[4][4] = {};
  bf16x8 pfc[4], pfn[4];
#pragma unroll
  for (int m = 0; m < 4; ++m)
    pfc[m] = *(const bf16x8*)(lAP + 0 * kChunk + (m * 16 + lr) * 72 + lg * 16);
#pragma unroll
  for (int kki = 0; kki < 16; ++kki) {
    if (kki < 13) {
#pragma unroll
      for (int n4 = 0; n4 < 4; ++n4)
        v3_[n4] = *(const bf16x8*)(vfb + (((size_t)(n4 * 16 + kki + 3)) << 9));
    }
    if (kki < 15) {
#pragma unroll
      for (int m = 0; m < 4; ++m)
        pfn[m] = *(const bf16x8*)(lAP + (kki + 1) * kChunk + (m * 16 + lr) * 72 +
                                  lg * 16);
    }
#pragma unroll
    for (int m = 0; m < 4; ++m)
#pragma unroll
      for (int n4 = 0; n4 < 4; ++n4)
        o[m][n4] = __builtin_amdgcn_mfma_f32_16x16x32_bf16(pfc[m], v0_[n4],
                                                           o[m][n4], 0, 0, 0);
#pragma unroll
    for (int m = 0; m < 4; ++m) pfc[m] = pfn[m];
#pragma unroll
    for (int n4 = 0; n4 < 4; ++n4) {
      v0_[n4] = v1_[n4];
      v1_[n4] = v2_[n4];
      v2_[n4] = v3_[n4];
    }
  }

  // ---- epilogue: slots [c2q | c*c2q] — pure stores (c in registers) -----
  float m_tile;
  {
    float v = mx[0][0];
#pragma unroll
    for (int m = 0; m < 4; ++m)
#pragma unroll
      for (int r = 0; r < 4; ++r) v = fmaxf(v, mx[m][r]);
    v = fmaxf(v, __shfl_xor(v, 16, 64));
    v = fmaxf(v, __shfl_xor(v, 32, 64));
    m_tile = v;
  }
  float u[4] = {};
  float zz = 0.f;
#pragma unroll
  for (int m = 0; m < 4; ++m)
#pragma unroll
    for (int r = 0; r < 4; ++r) {
      const int t = t0 + m * 16 + lg * 4 + r;
      const size_t rb = (size_t)(b * kT + t);
      float* orow = out + rb * kW;
      const float ev = __expf(mx[m][r] - m_tile);
      zz += ev;
#pragma unroll
      for (int n4 = 0; n4 < 4; ++n4) {
        const int d = w * 64 + n4 * 16 + lr;
        const float cvv = cfrag[m][n4][r];
        const float pv = o[m][n4][r];
        orow[kD + d] = pv;
        orow[2 * kD + d] = cvv * pv;
        u[n4] += ev * cvv;
      }
    }
#pragma unroll
  for (int n4 = 0; n4 < 4; ++n4) {
    u[n4] += __shfl_xor(u[n4], 16, 64);
    u[n4] += __shfl_xor(u[n4], 32, 64);
  }
  if (lg == 0) {
    float* ub = u_tile + ((size_t)(b * kTiles + tile)) * kD;
#pragma unroll
    for (int n4 = 0; n4 < 4; ++n4) ub[w * 64 + n4 * 16 + lr] = u[n4];
  }
  if (w == 0) {
    zz += __shfl_xor(zz, 16, 64);
    zz += __shfl_xor(zz, 32, 64);
    if (lane == 0) {
      mz[b * 64 + tile] = m_tile;
      mz[b * 64 + 32 + tile] = zz;
    }
  }
}

// per-tile: recompute q2c[b,:] from mz+u_tile (L2-warm); slot3 = slot0 * q2c
__global__ __launch_bounds__(512) void slot3_merge_kernel(
    const float* __restrict__ mz, const float* __restrict__ u_tile,
    float* __restrict__ out) {
  const int b = blockIdx.y;
  const int tile = blockIdx.x;
  const int t0 = tile * kRows;
  const int tid = threadIdx.x;
  __shared__ float sM[32], sZ[32];
  __shared__ float sq2c[kD];
  if (tid < 32) {
    sM[tid] = mz[b * 64 + tid];
    sZ[tid] = mz[b * 64 + 32 + tid];
  }
  __syncthreads();
  {
    float M = sM[0];
#pragma unroll
    for (int k = 1; k < 32; ++k) M = fmaxf(M, sM[k]);
    float Z = 0.f;
    float s = 0.f;
#pragma unroll
    for (int k = 0; k < 32; ++k) {
      const float wk = __expf(sM[k] - M);
      Z += wk * sZ[k];
      s += wk * u_tile[((size_t)(b * kTiles + k)) * kD + tid];
    }
    sq2c[tid] = s / Z;
  }
  __syncthreads();
  const int srow = tid >> 3;       // 0..63
  const int col4 = (tid & 7) * 4;  // 0..28
  const size_t rb = (size_t)(b * kT + t0 + srow);
  float* orow = out + rb * kW;     // slot0 holds c (L3-resident)
#pragma unroll
  for (int j = 0; j < 16; ++j) {
    const int col = col4 + j * 32;
    const f32x4 cv = *(const f32x4*)(orow + col);
    const f32x4 qc = *(const f32x4*)(sq2c + col);
    *(f32x4*)(orow + 3 * kD + col) = cv * qc;
  }
}

extern "C" void kernel_launch(void* const* d_in, const int* in_sizes, int n_in,
                              void* d_out, int out_size, void* d_ws, size_t ws_size,
                              hipStream_t stream) {
  const float* c    = (const float*)d_in[0];
  const float* q    = (const float*)d_in[1];
  const float* w_c  = (const float*)d_in[2];
  const float* b_c  = (const float*)d_in[3];
  const float* w_q  = (const float*)d_in[4];
  const float* b_q  = (const float*)d_in[5];
  const float* w_cq = (const float*)d_in[6];
  const float* b_cq = (const float*)d_in[7];
  float* out = (float*)d_out;
  float* ws = (float*)d_ws;

  // ws layout (floats): sq 4096 | mz 512 | u_tile 131072 ;
  // then bf16: qf 2M | vf 2M   (~9 MB total)
  float* sq     = ws;
  float* mz     = sq + kB * kI;
  float* u_tile = mz + kB * 64;
  __bf16* qf = (__bf16*)(u_tile + (size_t)kB * kTiles * kD);
  __bf16* vf = qf + (size_t)kB * kI * kD;

  dim3 gp(96, kB);  // 32 qf-blocks + 64 vf-blocks per batch
  prep_kernel<<<gp, 256, 0, stream>>>(q, w_q, b_q, sq, qf, vf);

  dim3 gf(kTiles, kB);  // 32 x 8 = 256 blocks
  fused_attn<<<gf, 512, 0, stream>>>(c, qf, vf, w_cq, w_c, b_c, b_cq, sq, out,
                                     mz, u_tile);

  slot3_merge_kernel<<<gf, 512, 0, stream>>>(mz, u_tile, out);
}